// Round 11
// baseline (2249.948 us; speedup 1.0000x reference)
//
#include <hip/hip_runtime.h>
#include <math.h>

#define BN 32
#define DN 128
#define GW 640            // 5*DN gate width
#define NSTEP 31
#define NT 1024

// probe keep-alive output layout (within the Gh scratch region, re-inited before main)
#define P_HID  0
#define P_SC   4096
#define P_SCAL 5120
#define P_EDGE 5122

__device__ __forceinline__ float sigf(float x) { return 1.0f / (1.0f + expf(-x)); }

// ---------------------------------------------------------------- k1: leaf
__global__ __launch_bounds__(256)
void leaf_kernel(const float* __restrict__ x_emb, const float* __restrict__ W_leaf,
                 const float* __restrict__ b_leaf, const int* __restrict__ bidx,
                 float* __restrict__ hidden0, float* __restrict__ cell0)
{
    const int i = blockIdx.x;        // row 0..31
    const int c = threadIdx.x;       // col 0..255
    const float* xr = x_emb + bidx[i] * DN;
    float acc = b_leaf[c];
    #pragma unroll 16
    for (int j = 0; j < DN; ++j) acc = fmaf(xr[j], W_leaf[j * 256 + c], acc);
    if (c < DN) hidden0[i * DN + c] = acc;
    else        cell0[i * DN + (c - DN)] = acc;
}

// ---------------------------------------------------------------- k2: tables
__global__ __launch_bounds__(256)
void init2_kernel(const float* __restrict__ W_tree, const float* __restrict__ W_a1,
                  const float* __restrict__ hidden0,
                  float* __restrict__ Gh, float* __restrict__ Gd,
                  float* __restrict__ uT0, float* __restrict__ vT0)
{
    __shared__ float sh_h[BN][DN + 1];
    for (int i = threadIdx.x; i < BN * DN; i += 256)
        sh_h[i >> 7][i & 127] = hidden0[i];
    __syncthreads();
    const int task = blockIdx.x * 256 + threadIdx.x;   // grid 24*256 = 6144
    float acc[8];
    #pragma unroll
    for (int r = 0; r < 8; ++r) acc[r] = 0.0f;
    if (task < 5120) {
        const int rg = task & 3, r0 = rg * 8;
        const int cc = task >> 2;                       // 0..1279
        const int c  = (cc < GW) ? cc : cc - GW;
        const float* Wt = W_tree + ((cc < GW) ? 0 : DN * GW) + c;
        #pragma unroll 8
        for (int k = 0; k < DN; ++k) {
            const float w = Wt[k * GW];
            #pragma unroll
            for (int r = 0; r < 8; ++r) acc[r] = fmaf(sh_h[r0 + r][k], w, acc[r]);
        }
        float* Gt = ((cc < GW) ? Gh : Gd) + c;
        #pragma unroll
        for (int r = 0; r < 8; ++r) Gt[(r0 + r) * GW] = acc[r];
    } else if (task < 6144) {
        const int tt = task - 5120;
        const int rg = tt & 3, r0 = rg * 8;
        const int cc = tt >> 2;                         // 0..255
        const int k  = cc & 127;
        const float* Wp = W_a1 + ((cc < DN) ? 0 : DN * DN) + k;
        #pragma unroll 8
        for (int j = 0; j < DN; ++j) {
            const float w = Wp[j * DN];
            #pragma unroll
            for (int r = 0; r < 8; ++r) acc[r] = fmaf(sh_h[r0 + r][j], w, acc[r]);
        }
        float* dst = ((cc < DN) ? uT0 : vT0) + k * BN + r0;
        #pragma unroll
        for (int r = 0; r < 8; ++r) dst[r] = acc[r];
    }
}

// ---------------------------------------------------------------- k3: main loop (UNCHANGED from measured 723us version)
__global__ __launch_bounds__(NT)
void main_kernel(const float* __restrict__ W_tree, const float* __restrict__ b_tree,
                 const float* __restrict__ W_a1, const float* __restrict__ b_a1,
                 const float* __restrict__ W_a2, const float* __restrict__ b_a2,
                 const int* __restrict__ bidx,
                 const float* __restrict__ hidden0, const float* __restrict__ cell0,
                 const float* __restrict__ uT0, const float* __restrict__ vT0,
                 float* Gh, float* Gd,
                 float* __restrict__ out)
{
    __shared__ float sh_hidden[BN][DN + 1];
    __shared__ float sh_cell[BN][DN + 1];
    __shared__ float sh_uT[DN][BN + 1];
    __shared__ float sh_vT[DN][BN + 1];
    __shared__ float sh_score[BN * BN];
    __shared__ float sh_btree[GW];
    __shared__ float sh_w2[DN], sh_b1[DN];
    __shared__ int   sh_bidx[BN];
    __shared__ unsigned sh_maskbits;
    __shared__ int sh_head, sh_dep;
    __shared__ float sh_b2;

    const int tid  = threadIdx.x;
    const int lane = tid & 63;
    const int wid  = tid >> 6;

    for (int i = tid; i < BN * DN; i += NT) {
        sh_hidden[i >> 7][i & 127] = hidden0[i];
        sh_cell[i >> 7][i & 127]   = cell0[i];
        sh_uT[i >> 5][i & 31] = uT0[i];
        sh_vT[i >> 5][i & 31] = vT0[i];
    }
    for (int i = tid; i < GW; i += NT) sh_btree[i] = b_tree[i];
    if (tid < DN) { sh_w2[tid] = W_a2[tid]; sh_b1[tid] = b_a1[tid]; }
    if (tid < BN) sh_bidx[tid] = bidx[tid];
    if (tid == 0) { sh_b2 = b_a2[0]; sh_maskbits = 0xFFFFFFFFu; }
    __syncthreads();

    const int f_o = tid >> 4, f_sub = tid & 15;
    float w2r[8], b1r[8];
    #pragma unroll
    for (int i = 0; i < 8; ++i) { w2r[i] = sh_w2[f_sub * 8 + i]; b1r[i] = sh_b1[f_sub * 8 + i]; }

    {
        const int h = tid >> 5, d = tid & 31;
        float acc = sh_b2;
        #pragma unroll 8
        for (int k = 0; k < DN; ++k) {
            const float pre = sh_uT[k][h] + sh_vT[k][d] + sh_b1[k];
            acc = fmaf(sh_w2[k], fmaxf(pre, 0.0f), acc);
        }
        sh_score[h * BN + d] = acc;
    }
    __syncthreads();

    float lps_sum = 0.0f, ents_sum = 0.0f;
    int prev_head = -1;

    for (int t = 0; t < NSTEP; ++t) {
        if (wid == 0) {
            const unsigned mbits = sh_maskbits;
            float s_[16]; bool v_[16];
            float m = -3.0e38f;
            #pragma unroll
            for (int i = 0; i < 16; ++i) {
                const int flat = i * 64 + lane;
                const int h = flat >> 5, d = flat & 31;
                const float sc = sh_score[flat];
                const bool vv = (h != d) && ((mbits >> d) & 1u);
                s_[i] = sc; v_[i] = vv;
                m = vv ? fmaxf(m, sc) : m;
            }
            #pragma unroll
            for (int off = 1; off < 64; off <<= 1) m = fmaxf(m, __shfl_xor(m, off));
            float e = 0.0f, s1 = 0.0f; int cand = 0x7fffffff;
            #pragma unroll
            for (int i = 0; i < 16; ++i) {
                if (v_[i]) {
                    const float x = s_[i] - m;
                    const float ex = expf(x);
                    e += ex; s1 += ex * x;
                    if (s_[i] == m) cand = min(cand, i * 64 + lane);
                }
            }
            #pragma unroll
            for (int off = 1; off < 64; off <<= 1) {
                e    += __shfl_xor(e, off);
                s1   += __shfl_xor(s1, off);
                cand  = min(cand, __shfl_xor(cand, off));
            }
            const float logE = logf(e);
            lps_sum -= logE;
            ents_sum -= (s1 / e - logE) / logf((float)((BN - t) * (BN - 1)));
            if (lane == 0) {
                const int hh = cand >> 5, dd = cand & 31;
                sh_head = hh; sh_dep = dd;
                sh_maskbits = mbits & ~(1u << dd);
                out[BN * DN + 2 + 2 * t]     = (float)sh_bidx[hh];
                out[BN * DN + 2 + 2 * t + 1] = (float)sh_bidx[dd];
            }
        } else if (prev_head >= 0) {
            const float* hrow = sh_hidden[prev_head];
            const int task = tid - 64;
            if (task < GW) {
                const int cc  = task * 2;
                const int col = (cc < GW) ? cc : cc - GW;
                const float2* Wt2 = (const float2*)(W_tree + ((cc < GW) ? 0 : DN * GW) + col);
                float ax = 0.0f, ay = 0.0f;
                #pragma unroll 16
                for (int k = 0; k < DN; ++k) {
                    const float2 w = Wt2[k * (GW / 2)];
                    const float hv = hrow[k];
                    ax = fmaf(hv, w.x, ax);
                    ay = fmaf(hv, w.y, ay);
                }
                float* Gt = ((cc < GW) ? Gh : Gd) + prev_head * GW + col;
                Gt[0] = ax; Gt[1] = ay;
            }
        }
        __syncthreads();

        const int head = sh_head, dep = sh_dep;

        if (tid < DN) {
            const int k = tid;
            const float* gh = Gh + head * GW + k;
            const float* gd = Gd + dep  * GW + k;
            const float z0 = gh[0]      + gd[0]      + sh_btree[k];
            const float z1 = gh[DN]     + gd[DN]     + sh_btree[DN + k];
            const float z2 = gh[2 * DN] + gd[2 * DN] + sh_btree[2 * DN + k];
            const float z3 = gh[3 * DN] + gd[3 * DN] + sh_btree[3 * DN + k];
            const float z4 = gh[4 * DN] + gd[4 * DN] + sh_btree[4 * DN + k];
            const float ig = sigf(z0), fl = sigf(z1), fr = sigf(z2), og = sigf(z4);
            const float gg = tanhf(z3);
            const float c  = ig * gg + fl * sh_cell[head][k] + fr * sh_cell[dep][k];
            sh_cell[head][k]   = c;
            sh_hidden[head][k] = og * tanhf(c);
        }
        __syncthreads();

        if (tid < 2 * DN) {
            const int k = tid & 127;
            const float* Wp = W_a1 + ((tid < DN) ? 0 : DN * DN) + k;
            const float* hrow = sh_hidden[head];
            float acc = 0.0f;
            #pragma unroll 32
            for (int j = 0; j < DN; ++j) acc = fmaf(hrow[j], Wp[j * DN], acc);
            if (tid < DN) sh_uT[k][head] = acc; else sh_vT[k][head] = acc;
        }
        __syncthreads();

        {
            const int hh = (f_o < BN) ? head : (f_o - BN);
            const int dd = (f_o < BN) ? f_o : head;
            float p = 0.0f;
            #pragma unroll
            for (int i = 0; i < 8; ++i) {
                const int k = f_sub * 8 + i;
                const float pre = sh_uT[k][hh] + sh_vT[k][dd] + b1r[i];
                p = fmaf(w2r[i], fmaxf(pre, 0.0f), p);
            }
            #pragma unroll
            for (int off = 8; off > 0; off >>= 1) p += __shfl_down(p, off, 16);
            if (f_sub == 0 && hh != dd) sh_score[hh * BN + dd] = p + sh_b2;
        }
        __syncthreads();

        prev_head = head;
    }

    for (int w = tid; w < BN * DN; w += NT) out[w] = sh_hidden[w >> 7][w & 127];
    if (tid == 0) {
        out[BN * DN]     = lps_sum;
        out[BN * DN + 1] = ents_sum / (float)NSTEP;
    }
}

// ---------------------------------------------------------------- probes
// MODE: 0=full replica, 1=no G-refresh, 2=no softmax (fixed schedule), 3=barrier skeleton.
// Writes keep-alive state ONLY to pout (ws scratch, re-inited before main).
template<int MODE>
__device__ __forceinline__
void probe_body(const float* __restrict__ W_tree, const float* __restrict__ b_tree,
                const float* __restrict__ W_a1, const float* __restrict__ b_a1,
                const float* __restrict__ W_a2, const float* __restrict__ b_a2,
                const float* __restrict__ hidden0, const float* __restrict__ cell0,
                const float* __restrict__ uT0, const float* __restrict__ vT0,
                float* Gh, float* Gd, float* pout)
{
    constexpr bool DO_SM  = (MODE == 0 || MODE == 1);
    constexpr bool DO_REF = (MODE == 0 || MODE == 2);
    constexpr bool DO_PH  = (MODE != 3);

    __shared__ float sh_hidden[BN][DN + 1];
    __shared__ float sh_cell[BN][DN + 1];
    __shared__ float sh_uT[DN][BN + 1];
    __shared__ float sh_vT[DN][BN + 1];
    __shared__ float sh_score[BN * BN];
    __shared__ float sh_btree[GW];
    __shared__ float sh_w2[DN], sh_b1[DN];
    __shared__ unsigned sh_maskbits;
    __shared__ int sh_head, sh_dep;
    __shared__ float sh_b2;

    const int tid  = threadIdx.x;
    const int lane = tid & 63;
    const int wid  = tid >> 6;

    for (int i = tid; i < BN * DN; i += NT) {
        sh_hidden[i >> 7][i & 127] = hidden0[i];
        sh_cell[i >> 7][i & 127]   = cell0[i];
        sh_uT[i >> 5][i & 31] = uT0[i];
        sh_vT[i >> 5][i & 31] = vT0[i];
    }
    for (int i = tid; i < GW; i += NT) sh_btree[i] = b_tree[i];
    if (tid < DN) { sh_w2[tid] = W_a2[tid]; sh_b1[tid] = b_a1[tid]; }
    if (tid == 0) { sh_b2 = b_a2[0]; sh_maskbits = 0xFFFFFFFFu; }
    __syncthreads();

    const int f_o = tid >> 4, f_sub = tid & 15;
    float w2r[8], b1r[8];
    #pragma unroll
    for (int i = 0; i < 8; ++i) { w2r[i] = sh_w2[f_sub * 8 + i]; b1r[i] = sh_b1[f_sub * 8 + i]; }

    {
        const int h = tid >> 5, d = tid & 31;
        float acc = sh_b2;
        #pragma unroll 8
        for (int k = 0; k < DN; ++k) {
            const float pre = sh_uT[k][h] + sh_vT[k][d] + sh_b1[k];
            acc = fmaf(sh_w2[k], fmaxf(pre, 0.0f), acc);
        }
        sh_score[h * BN + d] = acc;
    }
    __syncthreads();

    float lps_sum = 0.0f, ents_sum = 0.0f;
    int prev_head = -1;

    for (int t = 0; t < NSTEP; ++t) {
        // ===== phase 1
        if (wid == 0) {
            if constexpr (DO_SM) {
                const unsigned mbits = sh_maskbits;
                float s_[16]; bool v_[16];
                float m = -3.0e38f;
                #pragma unroll
                for (int i = 0; i < 16; ++i) {
                    const int flat = i * 64 + lane;
                    const int h = flat >> 5, d = flat & 31;
                    const float sc = sh_score[flat];
                    const bool vv = (h != d) && ((mbits >> d) & 1u);
                    s_[i] = sc; v_[i] = vv;
                    m = vv ? fmaxf(m, sc) : m;
                }
                #pragma unroll
                for (int off = 1; off < 64; off <<= 1) m = fmaxf(m, __shfl_xor(m, off));
                float e = 0.0f, s1 = 0.0f; int cand = 0x7fffffff;
                #pragma unroll
                for (int i = 0; i < 16; ++i) {
                    if (v_[i]) {
                        const float x = s_[i] - m;
                        const float ex = expf(x);
                        e += ex; s1 += ex * x;
                        if (s_[i] == m) cand = min(cand, i * 64 + lane);
                    }
                }
                #pragma unroll
                for (int off = 1; off < 64; off <<= 1) {
                    e    += __shfl_xor(e, off);
                    s1   += __shfl_xor(s1, off);
                    cand  = min(cand, __shfl_xor(cand, off));
                }
                const float logE = logf(e);
                lps_sum -= logE;
                ents_sum -= (s1 / e - logE) / logf((float)((BN - t) * (BN - 1)));
                if (lane == 0) {
                    const int hh = cand >> 5, dd = cand & 31;
                    sh_head = hh; sh_dep = dd;
                    sh_maskbits = mbits & ~(1u << dd);
                    pout[P_EDGE + 2 * t]     = (float)hh;
                    pout[P_EDGE + 2 * t + 1] = (float)dd;
                }
            } else {
                if (lane == 0) {
                    int hh = (3 * t + 5) & 31;
                    int dd = (7 * t + 2) & 31;
                    if (hh == dd) dd = (dd + 1) & 31;
                    sh_head = hh; sh_dep = dd;
                    pout[P_EDGE + 2 * t]     = (float)hh;
                    pout[P_EDGE + 2 * t + 1] = (float)dd;
                }
            }
        } else {
            if constexpr (DO_REF) {
                if (prev_head >= 0) {
                    const float* hrow = sh_hidden[prev_head];
                    const int task = tid - 64;
                    if (task < GW) {
                        const int cc  = task * 2;
                        const int col = (cc < GW) ? cc : cc - GW;
                        const float2* Wt2 = (const float2*)(W_tree + ((cc < GW) ? 0 : DN * GW) + col);
                        float ax = 0.0f, ay = 0.0f;
                        #pragma unroll 16
                        for (int k = 0; k < DN; ++k) {
                            const float2 w = Wt2[k * (GW / 2)];
                            const float hv = hrow[k];
                            ax = fmaf(hv, w.x, ax);
                            ay = fmaf(hv, w.y, ay);
                        }
                        float* Gt = ((cc < GW) ? Gh : Gd) + prev_head * GW + col;
                        Gt[0] = ax; Gt[1] = ay;
                    }
                }
            }
        }
        __syncthreads();

        const int head = sh_head, dep = sh_dep;

        // ===== phase 2
        if constexpr (DO_PH) {
            if (tid < DN) {
                const int k = tid;
                const float* gh = Gh + head * GW + k;
                const float* gd = Gd + dep  * GW + k;
                const float z0 = gh[0]      + gd[0]      + sh_btree[k];
                const float z1 = gh[DN]     + gd[DN]     + sh_btree[DN + k];
                const float z2 = gh[2 * DN] + gd[2 * DN] + sh_btree[2 * DN + k];
                const float z3 = gh[3 * DN] + gd[3 * DN] + sh_btree[3 * DN + k];
                const float z4 = gh[4 * DN] + gd[4 * DN] + sh_btree[4 * DN + k];
                const float ig = sigf(z0), fl = sigf(z1), fr = sigf(z2), og = sigf(z4);
                const float gg = tanhf(z3);
                const float c  = ig * gg + fl * sh_cell[head][k] + fr * sh_cell[dep][k];
                sh_cell[head][k]   = c;
                sh_hidden[head][k] = og * tanhf(c);
            }
        } else {
            if (tid < DN) sh_hidden[head][tid] = fmaf(sh_hidden[head][tid], 0.9999999f, 1e-9f);
        }
        __syncthreads();

        // ===== phase 3
        if constexpr (DO_PH) {
            if (tid < 2 * DN) {
                const int k = tid & 127;
                const float* Wp = W_a1 + ((tid < DN) ? 0 : DN * DN) + k;
                const float* hrow = sh_hidden[head];
                float acc = 0.0f;
                #pragma unroll 32
                for (int j = 0; j < DN; ++j) acc = fmaf(hrow[j], Wp[j * DN], acc);
                if (tid < DN) sh_uT[k][head] = acc; else sh_vT[k][head] = acc;
            }
        } else {
            if (tid == 0) sh_uT[t & 127][head] += 1e-9f;
        }
        __syncthreads();

        // ===== phase 4
        if constexpr (DO_PH) {
            const int hh = (f_o < BN) ? head : (f_o - BN);
            const int dd = (f_o < BN) ? f_o : head;
            float p = 0.0f;
            #pragma unroll
            for (int i = 0; i < 8; ++i) {
                const int k = f_sub * 8 + i;
                const float pre = sh_uT[k][hh] + sh_vT[k][dd] + b1r[i];
                p = fmaf(w2r[i], fmaxf(pre, 0.0f), p);
            }
            #pragma unroll
            for (int off = 8; off > 0; off >>= 1) p += __shfl_down(p, off, 16);
            if (f_sub == 0 && hh != dd) sh_score[hh * BN + dd] = p + sh_b2;
        } else {
            if (tid == 0) sh_score[(t * 37) & 1023] += 1e-9f;
        }
        __syncthreads();

        prev_head = head;
    }

    for (int w = tid; w < BN * DN; w += NT) pout[P_HID + w] = sh_hidden[w >> 7][w & 127];
    for (int w = tid; w < BN * BN; w += NT) pout[P_SC + w] = sh_score[w];
    if (tid == 0) { pout[P_SCAL] = lps_sum; pout[P_SCAL + 1] = ents_sum; }
}

#define PROBE_ARGS const float* W_tree, const float* b_tree, const float* W_a1, \
                   const float* b_a1, const float* W_a2, const float* b_a2,     \
                   const float* hidden0, const float* cell0,                     \
                   const float* uT0, const float* vT0,                           \
                   float* Gh, float* Gd, float* pout
#define PROBE_PASS W_tree, b_tree, W_a1, b_a1, W_a2, b_a2, hidden0, cell0, uT0, vT0, Gh, Gd, pout

__global__ __launch_bounds__(NT) void probeA_full (PROBE_ARGS) { probe_body<0>(PROBE_PASS); }
__global__ __launch_bounds__(NT) void probeB_noref(PROBE_ARGS) { probe_body<1>(PROBE_PASS); }
__global__ __launch_bounds__(NT) void probeC_nosm (PROBE_ARGS) { probe_body<2>(PROBE_PASS); }
__global__ __launch_bounds__(NT) void probeD_bar  (PROBE_ARGS) { probe_body<3>(PROBE_PASS); }

extern "C" void kernel_launch(void* const* d_in, const int* in_sizes, int n_in,
                              void* d_out, int out_size, void* d_ws, size_t ws_size,
                              hipStream_t stream) {
    const float* x_emb  = (const float*)d_in[0];
    const float* W_leaf = (const float*)d_in[1];
    const float* b_leaf = (const float*)d_in[2];
    const float* W_tree = (const float*)d_in[3];
    const float* b_tree = (const float*)d_in[4];
    const float* W_a1   = (const float*)d_in[5];
    const float* b_a1   = (const float*)d_in[6];
    const float* W_a2   = (const float*)d_in[7];
    const float* b_a2   = (const float*)d_in[8];
    const int*   bidx   = (const int*)d_in[9];
    float* out = (float*)d_out;

    // ws layout (floats): hidden0[4096] cell0[4096] uT0[4096] vT0[4096] Gh[20480] Gd[20480]
    float* ws      = (float*)d_ws;
    float* hidden0 = ws;
    float* cell0   = ws + 4096;
    float* uT0     = ws + 8192;
    float* vT0     = ws + 12288;
    float* Gh      = ws + 16384;
    float* Gd      = Gh + BN * GW;
    float* pout    = Gh;   // probe keep-alive sink; Gh/Gd restored by the 2nd init2

    hipLaunchKernelGGL(leaf_kernel, dim3(BN), dim3(256), 0, stream,
                       x_emb, W_leaf, b_leaf, bidx, hidden0, cell0);
    hipLaunchKernelGGL(init2_kernel, dim3(24), dim3(256), 0, stream,
                       W_tree, W_a1, hidden0, Gh, Gd, uT0, vT0);

    // ---- diagnostic probes (write only to ws; timings read from rocprof table)
    hipLaunchKernelGGL(probeA_full,  dim3(1), dim3(NT), 0, stream,
                       W_tree, b_tree, W_a1, b_a1, W_a2, b_a2,
                       hidden0, cell0, uT0, vT0, Gh, Gd, pout);
    hipLaunchKernelGGL(probeC_nosm,  dim3(1), dim3(NT), 0, stream,
                       W_tree, b_tree, W_a1, b_a1, W_a2, b_a2,
                       hidden0, cell0, uT0, vT0, Gh, Gd, pout);
    hipLaunchKernelGGL(probeB_noref, dim3(1), dim3(NT), 0, stream,
                       W_tree, b_tree, W_a1, b_a1, W_a2, b_a2,
                       hidden0, cell0, uT0, vT0, Gh, Gd, pout);
    hipLaunchKernelGGL(probeD_bar,   dim3(1), dim3(NT), 0, stream,
                       W_tree, b_tree, W_a1, b_a1, W_a2, b_a2,
                       hidden0, cell0, uT0, vT0, Gh, Gd, pout);

    // restore G tables trashed by probes, then run the real kernel
    hipLaunchKernelGGL(init2_kernel, dim3(24), dim3(256), 0, stream,
                       W_tree, W_a1, hidden0, Gh, Gd, uT0, vT0);
    hipLaunchKernelGGL(main_kernel, dim3(1), dim3(NT), 0, stream,
                       W_tree, b_tree, W_a1, b_a1, W_a2, b_a2, bidx,
                       hidden0, cell0, uT0, vT0, Gh, Gd, out);
}